// Round 2
// baseline (94.836 us; speedup 1.0000x reference)
//
#include <hip/hip_runtime.h>
#include <math.h>

// TripletHard B=8192 D=128 NC=256. Round-21: PIN A-frags in registers.
// Round-0 counters showed work_kernel VGPR_Count=80 -- the 64-VGPR a[4][4]
// fragment set CANNOT be resident at 80 regs, so the compiler has been
// rematerializing it from global every jt (16 hidden global_load_dwordx4
// per thread per jt = 512 MB/dispatch of redundant L2 traffic, latency-
// serialized before the MFMAs). r19's lb(256,2) raised the CAP but the
// compiler still CHOSE 80 regs. Fix: make the values non-rematerializable
// with an opaque asm "+v" pin after the prologue load. Also pin li[][].
// Fusion from round-20 kept: 512 uniform blocks (2/CU), pos tracked inline
// as same-class online 2-min in the epilogue, no gen-2 tail.
//   prep : fp32->bf16 (RNE), K-major fbT, lsq=(sq,lblbits) of rounded values.
//   work : 512 blocks, wave tile 64x32 (mf=4, nf=2), A-frags pinned,
//          B via LDS dbuf, 16 jt. Tracks n1 (diff-class min) + s1,s2
//          (same-class two smallest) per element.
//   merge: combine 16 (n1,s1,s2) slices -> mean hinge (device atomics).
// fbT8[kc*8192 + row] = features[row][kc*8..kc*8+7], kc=0..15.

#define BN 8192
#define MARGIN_F 1.0f
#define EPS_F 1e-5f

typedef __attribute__((ext_vector_type(8))) short short8;
typedef __attribute__((ext_vector_type(4))) float floatx4;

__device__ __forceinline__ unsigned short bf16_rne(float x, float& r) {
    unsigned u = __float_as_uint(x);
    u += 0x7FFF + ((u >> 16) & 1);
    unsigned short h = (unsigned short)(u >> 16);
    r = __uint_as_float(((unsigned)h) << 16);
    return h;
}

// 8 threads/row (256 blocks): bf16 convert, K-major write, lsq=(sq, lblbits)
// from ROUNDED values. Also zero-inits g_acc/counter.
__global__ __launch_bounds__(256) void prep_kernel(const float* __restrict__ f,
                                                   const int* __restrict__ lbl,
                                                   short8* __restrict__ fbT,
                                                   float2* __restrict__ lsq,
                                                   float* __restrict__ g_acc,
                                                   unsigned* __restrict__ counter) {
    int gid = blockIdx.x * 256 + threadIdx.x;  // 0..65535
    if (gid == 0) { *g_acc = 0.f; *counter = 0u; }
    int row = gid >> 3, part = gid & 7;
    const float4* f4 = (const float4*)f + (size_t)row * 32 + part * 4;
    float s = 0.f;
#pragma unroll
    for (int cc = 0; cc < 2; ++cc) {  // chunk kc = part*2 + cc
        float4 v0 = f4[cc * 2], v1 = f4[cc * 2 + 1];
        float r0, r1, r2, r3, r4, r5, r6, r7;
        short8 o;
        o[0] = (short)bf16_rne(v0.x, r0);
        o[1] = (short)bf16_rne(v0.y, r1);
        o[2] = (short)bf16_rne(v0.z, r2);
        o[3] = (short)bf16_rne(v0.w, r3);
        o[4] = (short)bf16_rne(v1.x, r4);
        o[5] = (short)bf16_rne(v1.y, r5);
        o[6] = (short)bf16_rne(v1.z, r6);
        o[7] = (short)bf16_rne(v1.w, r7);
        fbT[(size_t)(part * 2 + cc) * BN + row] = o;
        s += r0 * r0 + r1 * r1 + r2 * r2 + r3 * r3 +
             r4 * r4 + r5 * r5 + r6 * r6 + r7 * r7;
    }
    s += __shfl_xor(s, 1, 8);
    s += __shfl_xor(s, 2, 8);
    s += __shfl_xor(s, 4, 8);
    if (part == 0) {
        float2 p;
        p.x = s;
        p.y = __int_as_float(lbl[row]);
        lsq[row] = p;
    }
}

// Stage one 32-col B-tile (16 chunks x 32 cols = 8 KB) into LDS: each wave
// issues 2 global_load_lds(16B). LDS dest is wave-uniform; HW adds lane*16.
// Layout: tile[kc*32 + col], kc = lane>>5 within each 64-slot instr.
__device__ __forceinline__ void stage_tile(const short8* __restrict__ fbT,
                                           short8* tile, int j0, int wv, int lane) {
#pragma unroll
    for (int it = 0; it < 2; ++it) {
        int s = wv * 128 + it * 64;  // wave-uniform slot base
        int kc = (s >> 5) + (lane >> 5);
        int col = lane & 31;
        const short8* g = fbT + ((size_t)kc * BN + j0 + col);
        __builtin_amdgcn_global_load_lds(
            (const __attribute__((address_space(1))) void*)g,
            (__attribute__((address_space(3))) void*)(tile + s),
            16, 0, 0);
    }
}

// Fused work kernel: 512 uniform blocks (2/CU), wave tile 64x32.
// Per element track: n1 = min diff-class v, (s1,s2) = two smallest
// same-class v (self-pair included, as the reference requires).
__global__ __launch_bounds__(256, 2) void work_kernel(const short8* __restrict__ fbT,
                                                      const float2* __restrict__ lsq,
                                                      float* __restrict__ part_n1,
                                                      float* __restrict__ part_s1,
                                                      float* __restrict__ part_s2) {
    const int t = threadIdx.x;
    const int lane = t & 63;
    const int wv = t >> 6;
    const int q = lane >> 4, c = lane & 15;
    const int bid = blockIdx.x;

    __shared__ short8 Bt[2][512];    // 2 x 8 KB, [kc*32 + col]
    __shared__ float2 lsq_sh[512];   // block's j-stripe (sq, lblbits)

    const int i0 = (bid & 31) * 256 + wv * 64;  // 32 i-blocks x 4 waves x 64 rows
    const int g = bid >> 5;  // 0..15
    const int jb = g * 512;

    stage_tile(fbT, Bt[0], jb, wv, lane);  // tile 0 in flight

    // stage the whole stripe's (sq,label) once: 512 float2, 2 per thread
    lsq_sh[t] = lsq[jb + t];
    lsq_sh[t + 256] = lsq[jb + t + 256];

    short8 a[4][4];
#pragma unroll
    for (int mf = 0; mf < 4; ++mf) {
        int row = i0 + mf * 16 + c;
#pragma unroll
        for (int ks = 0; ks < 4; ++ks)
            a[mf][ks] = fbT[(size_t)(ks * 4 + q) * BN + row];
    }
    int li[4][4];
#pragma unroll
    for (int mf = 0; mf < 4; ++mf)
#pragma unroll
        for (int rg = 0; rg < 4; ++rg)
            li[mf][rg] = __float_as_int(lsq[i0 + mf * 16 + q * 4 + rg].y);

    // PIN: make a-frags and i-labels opaque asm outputs so the compiler
    // cannot rematerialize them from global inside the jt loop (the
    // VGPR_Count=80 remat pathology). Costs 0 instructions.
#pragma unroll
    for (int mf = 0; mf < 4; ++mf) {
#pragma unroll
        for (int ks = 0; ks < 4; ++ks)
            asm volatile("" : "+v"(a[mf][ks]));
#pragma unroll
        for (int rg = 0; rg < 4; ++rg)
            asm volatile("" : "+v"(li[mf][rg]));
    }

    float n1[4][4], s1[4][4], s2[4][4];
#pragma unroll
    for (int mf = 0; mf < 4; ++mf)
#pragma unroll
        for (int rg = 0; rg < 4; ++rg) {
            n1[mf][rg] = INFINITY;
            s1[mf][rg] = INFINITY;
            s2[mf][rg] = INFINITY;
        }

    __syncthreads();  // tile 0 + lsq_sh resident

    for (int jt = 0; jt < 16; ++jt) {
        const short8* cur = Bt[jt & 1];
        const int j0 = jb + jt * 32;
        // prefetch next tile NOW; it lands during this tile's compute
        if (jt < 15) stage_tile(fbT, Bt[1 - (jt & 1)], j0 + 32, wv, lane);

        int ljv[2]; float sjv[2];
#pragma unroll
        for (int nf = 0; nf < 2; ++nf) {
            float2 p = lsq_sh[jt * 32 + nf * 16 + c];  // LDS, no global latency
            sjv[nf] = p.x;
            ljv[nf] = __float_as_int(p.y);
        }

        floatx4 acc[4][2];
#pragma unroll
        for (int mf = 0; mf < 4; ++mf)
#pragma unroll
            for (int nf = 0; nf < 2; ++nf) acc[mf][nf] = (floatx4)0.f;

#pragma unroll
        for (int ks = 0; ks < 4; ++ks) {
            short8 b[2];
#pragma unroll
            for (int nf = 0; nf < 2; ++nf)
                b[nf] = cur[(ks * 4 + q) * 32 + nf * 16 + c];
#pragma unroll
            for (int mf = 0; mf < 4; ++mf)
#pragma unroll
                for (int nf = 0; nf < 2; ++nf)
                    acc[mf][nf] = __builtin_amdgcn_mfma_f32_16x16x32_bf16(
                        a[mf][ks], b[nf], acc[mf][nf], 0, 0, 0);
        }

        // fused epilogue: diff-class running min + same-class online 2-min
#pragma unroll
        for (int nf = 0; nf < 2; ++nf) {
#pragma unroll
            for (int mf = 0; mf < 4; ++mf)
#pragma unroll
                for (int rg = 0; rg < 4; ++rg) {
                    float v = fmaf(-2.0f, acc[mf][nf][rg], sjv[nf]);
                    bool same = (li[mf][rg] == ljv[nf]);
                    float vd = same ? INFINITY : v;
                    float vs = same ? v : INFINITY;
                    n1[mf][rg] = fminf(n1[mf][rg], vd);
                    s2[mf][rg] = fminf(s2[mf][rg], fmaxf(s1[mf][rg], vs));
                    s1[mf][rg] = fminf(s1[mf][rg], vs);
                }
        }
        // barrier at END: stage had the whole compute to land -> drain ~free
        __syncthreads();
    }

    // reduce across the 16 c-lanes sharing each accumulator row:
    // min for n1, two-smallest merge for (s1,s2)
#pragma unroll
    for (int m = 1; m < 16; m <<= 1) {
#pragma unroll
        for (int mf = 0; mf < 4; ++mf)
#pragma unroll
            for (int rg = 0; rg < 4; ++rg) {
                n1[mf][rg] = fminf(n1[mf][rg], __shfl_xor(n1[mf][rg], m, 16));
                float o1 = __shfl_xor(s1[mf][rg], m, 16);
                float o2 = __shfl_xor(s2[mf][rg], m, 16);
                float hi = fminf(fmaxf(s1[mf][rg], o1), fminf(s2[mf][rg], o2));
                s1[mf][rg] = fminf(s1[mf][rg], o1);
                s2[mf][rg] = hi;
            }
    }
    if (c == 0) {
#pragma unroll
        for (int mf = 0; mf < 4; ++mf)
#pragma unroll
            for (int rg = 0; rg < 4; ++rg) {
                int idx = g * BN + i0 + mf * 16 + q * 4 + rg;
                part_n1[idx] = n1[mf][rg];
                part_s1[idx] = s1[mf][rg];
                part_s2[idx] = s2[mf][rg];
            }
    }
}

// combine 16 (n1,s1,s2) slices -> hinge; atomic sum; last block writes mean
__global__ __launch_bounds__(128) void merge_kernel(const float* __restrict__ part_n1,
                                                    const float* __restrict__ part_s1,
                                                    const float* __restrict__ part_s2,
                                                    const float2* __restrict__ lsq,
                                                    float* __restrict__ g_acc,
                                                    unsigned* __restrict__ counter,
                                                    float* __restrict__ out) {
    int r = blockIdx.x * 128 + threadIdx.x;
    float n = INFINITY, s1 = INFINITY, s2 = INFINITY;
#pragma unroll
    for (int k = 0; k < 16; ++k) {
        n = fminf(n, part_n1[k * BN + r]);
        float a1 = part_s1[k * BN + r];
        float a2 = part_s2[k * BN + r];
        s2 = fminf(fmaxf(s1, a1), fminf(s2, a2));
        s1 = fminf(s1, a1);
    }
    float si = lsq[r].x;
    float pos = sqrtf(fmaxf(si + s2 + EPS_F, 0.f));
    float neg = sqrtf(fmaxf(si + n + EPS_F, 0.f));
    float h = fmaxf(MARGIN_F + pos - neg, 0.f);
    __shared__ float red[2];
#pragma unroll
    for (int m = 32; m >= 1; m >>= 1) h += __shfl_down(h, m, 64);
    if ((threadIdx.x & 63) == 0) red[threadIdx.x >> 6] = h;
    __syncthreads();
    if (threadIdx.x == 0) {
        atomicAdd(g_acc, red[0] + red[1]);
        __threadfence();
        unsigned old = atomicAdd(counter, 1u);
        if (old == 63u) {
            float tot = atomicAdd(g_acc, 0.0f);
            out[0] = tot / (float)BN;
        }
    }
}

extern "C" void kernel_launch(void* const* d_in, const int* in_sizes, int n_in,
                              void* d_out, int out_size, void* d_ws, size_t ws_size,
                              hipStream_t stream) {
    const float* f = (const float*)d_in[0];
    const int* lbl = (const int*)d_in[1];
    char* ws = (char*)d_ws;
    float2* lsq = (float2*)ws;                                  // 64 KB
    short8* fbT = (short8*)(ws + 65536);                        // 2 MB
    float* part_n1 = (float*)(ws + 65536 + 2097152);            // 512 KB
    float* part_s1 = (float*)(ws + 65536 + 2097152 + 524288);   // 512 KB
    float* part_s2 = (float*)(ws + 65536 + 2097152 + 1048576);  // 512 KB
    float* g_acc = (float*)(ws + 65536 + 2097152 + 1572864);
    unsigned* counter = (unsigned*)(g_acc + 1);
    float* out = (float*)d_out;

    prep_kernel<<<256, 256, 0, stream>>>(f, lbl, fbT, lsq, g_acc, counter);
    work_kernel<<<512, 256, 0, stream>>>(fbT, lsq, part_n1, part_s1, part_s2);
    merge_kernel<<<64, 128, 0, stream>>>(part_n1, part_s1, part_s2, lsq, g_acc, counter, out);
}

// Round 3
// 90.737 us; speedup vs baseline: 1.0452x; 1.0452x over previous
//
#include <hip/hip_runtime.h>
#include <math.h>

// TripletHard B=8192 D=128 NC=256. Round-22: DROP B LDS-staging (L2-fits).
// r21's pin was a null result -> remat was not the stall. Revised model:
// work ~45us vs ~9us throughput floor -> stall-bound, and the 16 per-jt
// __syncthreads (each a full vmcnt(0) drain due to global_load_lds) with
// only 2 waves/SIMD are the structural stall. fbT is 2 MB = L2-resident
// (guide common-mistake #7: staging L2-fit data is pure overhead). So:
// b-frags load DIRECT from global (L2 ~200cy, hidden by reg double-buffer
// + 2nd wave), jt-unrolled x2 so buffers are static-indexed. ZERO barriers
// in the main loop (one barrier total, after the 4KB lsq_sh fill).
// Fusion from r20 kept: 512 uniform blocks (2/CU), n1 + same-class (s1,s2)
// tracked inline; arithmetic bit-identical to r20/r21 -> absmax 0.
//   prep : fp32->bf16 (RNE), K-major fbT, lsq=(sq,lblbits) of rounded values.
//   work : 512 blocks, wave tile 64x32 (mf=4, nf=2), A-frags pinned,
//          B direct-from-L2 reg-dbuf, 16 jt, no jt barriers.
//   merge: combine 16 (n1,s1,s2) slices -> mean hinge (device atomics).
// fbT8[kc*8192 + row] = features[row][kc*8..kc*8+7], kc=0..15.

#define BN 8192
#define MARGIN_F 1.0f
#define EPS_F 1e-5f

typedef __attribute__((ext_vector_type(8))) short short8;
typedef __attribute__((ext_vector_type(4))) float floatx4;

__device__ __forceinline__ unsigned short bf16_rne(float x, float& r) {
    unsigned u = __float_as_uint(x);
    u += 0x7FFF + ((u >> 16) & 1);
    unsigned short h = (unsigned short)(u >> 16);
    r = __uint_as_float(((unsigned)h) << 16);
    return h;
}

// 8 threads/row (256 blocks): bf16 convert, K-major write, lsq=(sq, lblbits)
// from ROUNDED values. Also zero-inits g_acc/counter.
__global__ __launch_bounds__(256) void prep_kernel(const float* __restrict__ f,
                                                   const int* __restrict__ lbl,
                                                   short8* __restrict__ fbT,
                                                   float2* __restrict__ lsq,
                                                   float* __restrict__ g_acc,
                                                   unsigned* __restrict__ counter) {
    int gid = blockIdx.x * 256 + threadIdx.x;  // 0..65535
    if (gid == 0) { *g_acc = 0.f; *counter = 0u; }
    int row = gid >> 3, part = gid & 7;
    const float4* f4 = (const float4*)f + (size_t)row * 32 + part * 4;
    float s = 0.f;
#pragma unroll
    for (int cc = 0; cc < 2; ++cc) {  // chunk kc = part*2 + cc
        float4 v0 = f4[cc * 2], v1 = f4[cc * 2 + 1];
        float r0, r1, r2, r3, r4, r5, r6, r7;
        short8 o;
        o[0] = (short)bf16_rne(v0.x, r0);
        o[1] = (short)bf16_rne(v0.y, r1);
        o[2] = (short)bf16_rne(v0.z, r2);
        o[3] = (short)bf16_rne(v0.w, r3);
        o[4] = (short)bf16_rne(v1.x, r4);
        o[5] = (short)bf16_rne(v1.y, r5);
        o[6] = (short)bf16_rne(v1.z, r6);
        o[7] = (short)bf16_rne(v1.w, r7);
        fbT[(size_t)(part * 2 + cc) * BN + row] = o;
        s += r0 * r0 + r1 * r1 + r2 * r2 + r3 * r3 +
             r4 * r4 + r5 * r5 + r6 * r6 + r7 * r7;
    }
    s += __shfl_xor(s, 1, 8);
    s += __shfl_xor(s, 2, 8);
    s += __shfl_xor(s, 4, 8);
    if (part == 0) {
        float2 p;
        p.x = s;
        p.y = __int_as_float(lbl[row]);
        lsq[row] = p;
    }
}

// Fused work kernel: 512 uniform blocks (2/CU), wave tile 64x32.
// Per element track: n1 = min diff-class v, (s1,s2) = two smallest
// same-class v (self-pair included, as the reference requires).
__global__ __launch_bounds__(256, 2) void work_kernel(const short8* __restrict__ fbT,
                                                      const float2* __restrict__ lsq,
                                                      float* __restrict__ part_n1,
                                                      float* __restrict__ part_s1,
                                                      float* __restrict__ part_s2) {
    const int t = threadIdx.x;
    const int lane = t & 63;
    const int wv = t >> 6;
    const int q = lane >> 4, c = lane & 15;
    const int bid = blockIdx.x;

    __shared__ float2 lsq_sh[512];   // block's j-stripe (sq, lblbits) — 4 KB

    const int i0 = (bid & 31) * 256 + wv * 64;  // 32 i-blocks x 4 waves x 64 rows
    const int g = bid >> 5;  // 0..15
    const int jb = g * 512;

    // stage the whole stripe's (sq,label) once: 512 float2, 2 per thread
    lsq_sh[t] = lsq[jb + t];
    lsq_sh[t + 256] = lsq[jb + t + 256];

    short8 a[4][4];
#pragma unroll
    for (int mf = 0; mf < 4; ++mf) {
        int row = i0 + mf * 16 + c;
#pragma unroll
        for (int ks = 0; ks < 4; ++ks)
            a[mf][ks] = fbT[(size_t)(ks * 4 + q) * BN + row];
    }
    int li[4][4];
#pragma unroll
    for (int mf = 0; mf < 4; ++mf)
#pragma unroll
        for (int rg = 0; rg < 4; ++rg)
            li[mf][rg] = __float_as_int(lsq[i0 + mf * 16 + q * 4 + rg].y);

    // PIN: a-frags and i-labels non-rematerializable (r21; harmless, keeps
    // the prologue loads out of the jt loop).
#pragma unroll
    for (int mf = 0; mf < 4; ++mf) {
#pragma unroll
        for (int ks = 0; ks < 4; ++ks)
            asm volatile("" : "+v"(a[mf][ks]));
#pragma unroll
        for (int rg = 0; rg < 4; ++rg)
            asm volatile("" : "+v"(li[mf][rg]));
    }

    float n1[4][4], s1[4][4], s2[4][4];
#pragma unroll
    for (int mf = 0; mf < 4; ++mf)
#pragma unroll
        for (int rg = 0; rg < 4; ++rg) {
            n1[mf][rg] = INFINITY;
            s1[mf][rg] = INFINITY;
            s2[mf][rg] = INFINITY;
        }

    __syncthreads();  // lsq_sh resident — the ONLY barrier in this kernel

    // per-thread B base: row q of each chunk-group, col c within the j-tile
    const short8* bp = fbT + (size_t)q * BN + jb + c;

    // b-frag loader: 8 x global_load_dwordx4 from L2-resident fbT
#define LOADB(buf, jt_)                                                  \
    do {                                                                 \
        _Pragma("unroll") for (int ks = 0; ks < 4; ++ks)                 \
            _Pragma("unroll") for (int nf = 0; nf < 2; ++nf)             \
                buf[ks][nf] = bp[(size_t)ks * 4 * BN + (jt_) * 32 + nf * 16]; \
    } while (0)

    // one jt step: 32 MFMA + fused epilogue on a static-indexed buffer
#define STEP(buf, jt_)                                                   \
    do {                                                                 \
        int ljv[2]; float sjv[2];                                        \
        _Pragma("unroll") for (int nf = 0; nf < 2; ++nf) {               \
            float2 p = lsq_sh[(jt_) * 32 + nf * 16 + c];                 \
            sjv[nf] = p.x;                                               \
            ljv[nf] = __float_as_int(p.y);                               \
        }                                                                \
        floatx4 acc[4][2];                                               \
        _Pragma("unroll") for (int mf = 0; mf < 4; ++mf)                 \
            _Pragma("unroll") for (int nf = 0; nf < 2; ++nf)             \
                acc[mf][nf] = (floatx4)0.f;                              \
        _Pragma("unroll") for (int ks = 0; ks < 4; ++ks)                 \
            _Pragma("unroll") for (int mf = 0; mf < 4; ++mf)             \
                _Pragma("unroll") for (int nf = 0; nf < 2; ++nf)         \
                    acc[mf][nf] = __builtin_amdgcn_mfma_f32_16x16x32_bf16( \
                        a[mf][ks], buf[ks][nf], acc[mf][nf], 0, 0, 0);   \
        _Pragma("unroll") for (int nf = 0; nf < 2; ++nf)                 \
            _Pragma("unroll") for (int mf = 0; mf < 4; ++mf)             \
                _Pragma("unroll") for (int rg = 0; rg < 4; ++rg) {       \
                    float v = fmaf(-2.0f, acc[mf][nf][rg], sjv[nf]);     \
                    bool same = (li[mf][rg] == ljv[nf]);                 \
                    float vd = same ? INFINITY : v;                      \
                    float vs = same ? v : INFINITY;                      \
                    n1[mf][rg] = fminf(n1[mf][rg], vd);                  \
                    s2[mf][rg] = fminf(s2[mf][rg], fmaxf(s1[mf][rg], vs)); \
                    s1[mf][rg] = fminf(s1[mf][rg], vs);                  \
                }                                                        \
    } while (0)

    short8 bA[4][2], bB[4][2];
    LOADB(bA, 0);
#pragma unroll 1
    for (int jt = 0; jt < 16; jt += 2) {
        LOADB(bB, jt + 1);   // in flight over STEP(bA)'s MFMAs
        STEP(bA, jt);
        if (jt + 2 < 16) LOADB(bA, jt + 2);  // in flight over STEP(bB)
        STEP(bB, jt + 1);
    }
#undef LOADB
#undef STEP

    // reduce across the 16 c-lanes sharing each accumulator row:
    // min for n1, two-smallest merge for (s1,s2)
#pragma unroll
    for (int m = 1; m < 16; m <<= 1) {
#pragma unroll
        for (int mf = 0; mf < 4; ++mf)
#pragma unroll
            for (int rg = 0; rg < 4; ++rg) {
                n1[mf][rg] = fminf(n1[mf][rg], __shfl_xor(n1[mf][rg], m, 16));
                float o1 = __shfl_xor(s1[mf][rg], m, 16);
                float o2 = __shfl_xor(s2[mf][rg], m, 16);
                float hi = fminf(fmaxf(s1[mf][rg], o1), fminf(s2[mf][rg], o2));
                s1[mf][rg] = fminf(s1[mf][rg], o1);
                s2[mf][rg] = hi;
            }
    }
    if (c == 0) {
#pragma unroll
        for (int mf = 0; mf < 4; ++mf)
#pragma unroll
            for (int rg = 0; rg < 4; ++rg) {
                int idx = g * BN + i0 + mf * 16 + q * 4 + rg;
                part_n1[idx] = n1[mf][rg];
                part_s1[idx] = s1[mf][rg];
                part_s2[idx] = s2[mf][rg];
            }
    }
}

// combine 16 (n1,s1,s2) slices -> hinge; atomic sum; last block writes mean
__global__ __launch_bounds__(128) void merge_kernel(const float* __restrict__ part_n1,
                                                    const float* __restrict__ part_s1,
                                                    const float* __restrict__ part_s2,
                                                    const float2* __restrict__ lsq,
                                                    float* __restrict__ g_acc,
                                                    unsigned* __restrict__ counter,
                                                    float* __restrict__ out) {
    int r = blockIdx.x * 128 + threadIdx.x;
    float n = INFINITY, s1 = INFINITY, s2 = INFINITY;
#pragma unroll
    for (int k = 0; k < 16; ++k) {
        n = fminf(n, part_n1[k * BN + r]);
        float a1 = part_s1[k * BN + r];
        float a2 = part_s2[k * BN + r];
        s2 = fminf(fmaxf(s1, a1), fminf(s2, a2));
        s1 = fminf(s1, a1);
    }
    float si = lsq[r].x;
    float pos = sqrtf(fmaxf(si + s2 + EPS_F, 0.f));
    float neg = sqrtf(fmaxf(si + n + EPS_F, 0.f));
    float h = fmaxf(MARGIN_F + pos - neg, 0.f);
    __shared__ float red[2];
#pragma unroll
    for (int m = 32; m >= 1; m >>= 1) h += __shfl_down(h, m, 64);
    if ((threadIdx.x & 63) == 0) red[threadIdx.x >> 6] = h;
    __syncthreads();
    if (threadIdx.x == 0) {
        atomicAdd(g_acc, red[0] + red[1]);
        __threadfence();
        unsigned old = atomicAdd(counter, 1u);
        if (old == 63u) {
            float tot = atomicAdd(g_acc, 0.0f);
            out[0] = tot / (float)BN;
        }
    }
}

extern "C" void kernel_launch(void* const* d_in, const int* in_sizes, int n_in,
                              void* d_out, int out_size, void* d_ws, size_t ws_size,
                              hipStream_t stream) {
    const float* f = (const float*)d_in[0];
    const int* lbl = (const int*)d_in[1];
    char* ws = (char*)d_ws;
    float2* lsq = (float2*)ws;                                  // 64 KB
    short8* fbT = (short8*)(ws + 65536);                        // 2 MB
    float* part_n1 = (float*)(ws + 65536 + 2097152);            // 512 KB
    float* part_s1 = (float*)(ws + 65536 + 2097152 + 524288);   // 512 KB
    float* part_s2 = (float*)(ws + 65536 + 2097152 + 1048576);  // 512 KB
    float* g_acc = (float*)(ws + 65536 + 2097152 + 1572864);
    unsigned* counter = (unsigned*)(g_acc + 1);
    float* out = (float*)d_out;

    prep_kernel<<<256, 256, 0, stream>>>(f, lbl, fbT, lsq, g_acc, counter);
    work_kernel<<<512, 256, 0, stream>>>(fbT, lsq, part_n1, part_s1, part_s2);
    merge_kernel<<<64, 128, 0, stream>>>(part_n1, part_s1, part_s2, lsq, g_acc, counter, out);
}

// Round 5
// 85.973 us; speedup vs baseline: 1.1031x; 1.0554x over previous
//
#include <hip/hip_runtime.h>
#include <math.h>

// TripletHard B=8192 D=128 NC=256. Round-24: r23 occupancy structure with
// the diagonal self-exclusion SIGN BUG fixed.
//   i - j = dd + mf*16 + rg - nf*16, so self <=> dd == nf*16 - mf*16 - rg.
//   r23 compared against the negation -> self (v ~ -s_i, always the class
//   min) leaked into ss1 -> pos^2 ~ 0 -> absmax 1.84. One-line fix.
// Structure (unchanged from r23): grid 1024 (64 i-blocks x 16 stripes),
// wave tile 32x32 (mf=2, nf=2), lb(256,4) -> VGPR cap 128 -> 4 waves/SIMD
// of TLP to hide L2 latency; B single-buffered direct from L2-resident fbT;
// zero barriers in the jt loop. Epilogue: n1 (diff-class min) + ss1
// (same-class min excluding self; self-exclusion index-based, only in the
// 64 diagonal blocks via templated <DIAG>).
//   prep : fp32->bf16 (RNE), K-major fbT, lsq=(sq,lblbits) of rounded values.
//   work : 1024 blocks, 16 jt, B direct-from-L2, no jt barriers.
//   merge: min over 16 (n1,ss1) slices -> mean hinge (device atomics).
// fbT8[kc*8192 + row] = features[row][kc*8..kc*8+7], kc=0..15.

#define BN 8192
#define MARGIN_F 1.0f
#define EPS_F 1e-5f

typedef __attribute__((ext_vector_type(8))) short short8;
typedef __attribute__((ext_vector_type(4))) float floatx4;

__device__ __forceinline__ unsigned short bf16_rne(float x, float& r) {
    unsigned u = __float_as_uint(x);
    u += 0x7FFF + ((u >> 16) & 1);
    unsigned short h = (unsigned short)(u >> 16);
    r = __uint_as_float(((unsigned)h) << 16);
    return h;
}

// 8 threads/row (256 blocks): bf16 convert, K-major write, lsq=(sq, lblbits)
// from ROUNDED values. Also zero-inits g_acc/counter.
__global__ __launch_bounds__(256) void prep_kernel(const float* __restrict__ f,
                                                   const int* __restrict__ lbl,
                                                   short8* __restrict__ fbT,
                                                   float2* __restrict__ lsq,
                                                   float* __restrict__ g_acc,
                                                   unsigned* __restrict__ counter) {
    int gid = blockIdx.x * 256 + threadIdx.x;  // 0..65535
    if (gid == 0) { *g_acc = 0.f; *counter = 0u; }
    int row = gid >> 3, part = gid & 7;
    const float4* f4 = (const float4*)f + (size_t)row * 32 + part * 4;
    float s = 0.f;
#pragma unroll
    for (int cc = 0; cc < 2; ++cc) {  // chunk kc = part*2 + cc
        float4 v0 = f4[cc * 2], v1 = f4[cc * 2 + 1];
        float r0, r1, r2, r3, r4, r5, r6, r7;
        short8 o;
        o[0] = (short)bf16_rne(v0.x, r0);
        o[1] = (short)bf16_rne(v0.y, r1);
        o[2] = (short)bf16_rne(v0.z, r2);
        o[3] = (short)bf16_rne(v0.w, r3);
        o[4] = (short)bf16_rne(v1.x, r4);
        o[5] = (short)bf16_rne(v1.y, r5);
        o[6] = (short)bf16_rne(v1.z, r6);
        o[7] = (short)bf16_rne(v1.w, r7);
        fbT[(size_t)(part * 2 + cc) * BN + row] = o;
        s += r0 * r0 + r1 * r1 + r2 * r2 + r3 * r3 +
             r4 * r4 + r5 * r5 + r6 * r6 + r7 * r7;
    }
    s += __shfl_xor(s, 1, 8);
    s += __shfl_xor(s, 2, 8);
    s += __shfl_xor(s, 4, 8);
    if (part == 0) {
        float2 p;
        p.x = s;
        p.y = __int_as_float(lbl[row]);
        lsq[row] = p;
    }
}

// The 16-jt inner loop, templated on whether this block's i-range intersects
// its j-stripe (only 64 of 1024 blocks). DIAG adds the index-based self
// exclusion for ss1 (comparand is a compile-time constant per unrolled
// element): self <=> dd == nf*16 - mf*16 - rg.
template <bool DIAG>
__device__ __forceinline__ void jt_loop(const short8* __restrict__ bp,
                                        const float2* lsq_sh,
                                        const short8 a[2][4], const int li[2][4],
                                        float n1[2][4], float ss1[2][4],
                                        int c, int q, int i0, int jb) {
    for (int jt = 0; jt < 16; ++jt) {
        // single-buffer b-frags straight from L2-resident fbT; 4 waves/SIMD
        // of TLP hide the latency
        short8 b[4][2];
#pragma unroll
        for (int ks = 0; ks < 4; ++ks)
#pragma unroll
            for (int nf = 0; nf < 2; ++nf)
                b[ks][nf] = bp[(size_t)ks * 4 * BN + jt * 32 + nf * 16];

        int ljv[2]; float sjv[2];
#pragma unroll
        for (int nf = 0; nf < 2; ++nf) {
            float2 p = lsq_sh[jt * 32 + nf * 16 + c];
            sjv[nf] = p.x;
            ljv[nf] = __float_as_int(p.y);
        }

        // i - j = dd + mf*16 + rg - nf*16
        int dd = DIAG ? ((i0 + q * 4) - (jb + jt * 32 + c)) : 0;

        floatx4 acc[2][2];
#pragma unroll
        for (int mf = 0; mf < 2; ++mf)
#pragma unroll
            for (int nf = 0; nf < 2; ++nf) acc[mf][nf] = (floatx4)0.f;

#pragma unroll
        for (int ks = 0; ks < 4; ++ks)
#pragma unroll
            for (int mf = 0; mf < 2; ++mf)
#pragma unroll
                for (int nf = 0; nf < 2; ++nf)
                    acc[mf][nf] = __builtin_amdgcn_mfma_f32_16x16x32_bf16(
                        a[mf][ks], b[ks][nf], acc[mf][nf], 0, 0, 0);

#pragma unroll
        for (int nf = 0; nf < 2; ++nf)
#pragma unroll
            for (int mf = 0; mf < 2; ++mf)
#pragma unroll
                for (int rg = 0; rg < 4; ++rg) {
                    float v = fmaf(-2.0f, acc[mf][nf][rg], sjv[nf]);
                    bool same = (li[mf][rg] == ljv[nf]);
                    float vd = same ? INFINITY : v;
                    n1[mf][rg] = fminf(n1[mf][rg], vd);
                    bool excl = same;
                    if (DIAG) excl = same && (dd != (nf * 16 - mf * 16 - rg));
                    float vs = excl ? v : INFINITY;
                    ss1[mf][rg] = fminf(ss1[mf][rg], vs);
                }
    }
}

// Fused work kernel: 1024 blocks (4/CU), wave tile 32x32 (mf=2, nf=2).
// Per element: n1 = min diff-class v, ss1 = min same-class v excl self.
__global__ __launch_bounds__(256, 4) void work_kernel(const short8* __restrict__ fbT,
                                                      const float2* __restrict__ lsq,
                                                      float* __restrict__ part_n1,
                                                      float* __restrict__ part_p1) {
    const int t = threadIdx.x;
    const int lane = t & 63;
    const int wv = t >> 6;
    const int q = lane >> 4, c = lane & 15;
    const int bid = blockIdx.x;

    __shared__ float2 lsq_sh[512];  // block's j-stripe (sq, lblbits) — 4 KB

    const int ib = bid & 63;         // 64 i-blocks of 128 rows
    const int g = bid >> 6;          // 16 stripes
    const int i0 = ib * 128 + wv * 32;
    const int jb = g * 512;
    const bool diag = ((ib >> 2) == g);  // i-range intersects j-stripe

    // stage the stripe's (sq,label) once: 512 float2, 2 per thread
    lsq_sh[t] = lsq[jb + t];
    lsq_sh[t + 256] = lsq[jb + t + 256];

    short8 a[2][4];
#pragma unroll
    for (int mf = 0; mf < 2; ++mf) {
        int row = i0 + mf * 16 + c;
#pragma unroll
        for (int ks = 0; ks < 4; ++ks)
            a[mf][ks] = fbT[(size_t)(ks * 4 + q) * BN + row];
    }
    int li[2][4];
#pragma unroll
    for (int mf = 0; mf < 2; ++mf)
#pragma unroll
        for (int rg = 0; rg < 4; ++rg)
            li[mf][rg] = __float_as_int(lsq[i0 + mf * 16 + q * 4 + rg].y);

    float n1[2][4], ss1[2][4];
#pragma unroll
    for (int mf = 0; mf < 2; ++mf)
#pragma unroll
        for (int rg = 0; rg < 4; ++rg) {
            n1[mf][rg] = INFINITY;
            ss1[mf][rg] = INFINITY;
        }

    __syncthreads();  // lsq_sh resident — the ONLY barrier in this kernel

    const short8* bp = fbT + (size_t)q * BN + jb + c;
    if (diag)
        jt_loop<true>(bp, lsq_sh, a, li, n1, ss1, c, q, i0, jb);
    else
        jt_loop<false>(bp, lsq_sh, a, li, n1, ss1, c, q, i0, jb);

    // min-reduce across the 16 c-lanes sharing each accumulator row
#pragma unroll
    for (int m = 1; m < 16; m <<= 1) {
#pragma unroll
        for (int mf = 0; mf < 2; ++mf)
#pragma unroll
            for (int rg = 0; rg < 4; ++rg) {
                n1[mf][rg] = fminf(n1[mf][rg], __shfl_xor(n1[mf][rg], m, 16));
                ss1[mf][rg] = fminf(ss1[mf][rg], __shfl_xor(ss1[mf][rg], m, 16));
            }
    }
    if (c == 0) {
#pragma unroll
        for (int mf = 0; mf < 2; ++mf)
#pragma unroll
            for (int rg = 0; rg < 4; ++rg) {
                int idx = g * BN + i0 + mf * 16 + q * 4 + rg;
                part_n1[idx] = n1[mf][rg];
                part_p1[idx] = ss1[mf][rg];
            }
    }
}

// combine 16 (n1,ss1) slices -> hinge; atomic sum; last block writes mean
__global__ __launch_bounds__(128) void merge_kernel(const float* __restrict__ part_n1,
                                                    const float* __restrict__ part_p1,
                                                    const float2* __restrict__ lsq,
                                                    float* __restrict__ g_acc,
                                                    unsigned* __restrict__ counter,
                                                    float* __restrict__ out) {
    int r = blockIdx.x * 128 + threadIdx.x;
    float n = INFINITY, ss = INFINITY;
#pragma unroll
    for (int k = 0; k < 16; ++k) {
        n = fminf(n, part_n1[k * BN + r]);
        ss = fminf(ss, part_p1[k * BN + r]);
    }
    float si = lsq[r].x;
    float pos = sqrtf(fmaxf(si + ss + EPS_F, 0.f));
    float neg = sqrtf(fmaxf(si + n + EPS_F, 0.f));
    float h = fmaxf(MARGIN_F + pos - neg, 0.f);
    __shared__ float red[2];
#pragma unroll
    for (int m = 32; m >= 1; m >>= 1) h += __shfl_down(h, m, 64);
    if ((threadIdx.x & 63) == 0) red[threadIdx.x >> 6] = h;
    __syncthreads();
    if (threadIdx.x == 0) {
        atomicAdd(g_acc, red[0] + red[1]);
        __threadfence();
        unsigned old = atomicAdd(counter, 1u);
        if (old == 63u) {
            float tot = atomicAdd(g_acc, 0.0f);
            out[0] = tot / (float)BN;
        }
    }
}

extern "C" void kernel_launch(void* const* d_in, const int* in_sizes, int n_in,
                              void* d_out, int out_size, void* d_ws, size_t ws_size,
                              hipStream_t stream) {
    const float* f = (const float*)d_in[0];
    const int* lbl = (const int*)d_in[1];
    char* ws = (char*)d_ws;
    float2* lsq = (float2*)ws;                                  // 64 KB
    short8* fbT = (short8*)(ws + 65536);                        // 2 MB
    float* part_n1 = (float*)(ws + 65536 + 2097152);            // 512 KB
    float* part_p1 = (float*)(ws + 65536 + 2097152 + 524288);   // 512 KB
    float* g_acc = (float*)(ws + 65536 + 2097152 + 1048576);
    unsigned* counter = (unsigned*)(g_acc + 1);
    float* out = (float*)d_out;

    prep_kernel<<<256, 256, 0, stream>>>(f, lbl, fbT, lsq, g_acc, counter);
    work_kernel<<<1024, 256, 0, stream>>>(fbT, lsq, part_n1, part_p1);
    merge_kernel<<<64, 128, 0, stream>>>(part_n1, part_p1, lsq, g_acc, counter, out);
}

// Round 6
// 85.236 us; speedup vs baseline: 1.1126x; 1.0086x over previous
//
#include <hip/hip_runtime.h>
#include <math.h>

// TripletHard B=8192 D=128 NC=256. Round-25: LDS B-staging AT 4 BLOCKS/CU.
// r24 (direct-L2 B, 4 waves/SIMD) = 86.0us. Its remaining floor: every wave
// privately pulls B from L2 -> 1024x4x16x8KB = 512 MB/dispatch ~ 15us of L2
// BW + exposed L2 latency (single-buffered, no reg room for dbuf at the 128
// cap). Fix: stage B once per block via global_load_lds (4-wave shared ->
// 128 MB L2 traffic, ~4us) with r0's proven prefetch/barrier-at-end dbuf.
// The old barrier pathology was a 2-blocks/CU artifact: all CU waves sat in
// the same vmcnt(0)+s_barrier. At 4 independent blocks/CU the other blocks
// keep the pipes busy while one drains. = r0 skeleton + r24 occupancy +
// slim fused epilogue.
//   prep : fp32->bf16 (RNE), K-major fbT, lsq=(sq,lblbits) of rounded values.
//   work : 1024 blocks (64 i-blocks x 16 stripes), 4 waves, wave tile 32x32
//          (mf=2, nf=2), lb(256,4) -> <=128 VGPR -> 4 blocks/CU. B via LDS
//          dbuf (global_load_lds 16B), 16 jt, barrier at loop end. Epilogue:
//          n1 (diff-class min) + ss1 (same-class min excl self; index-based
//          exclusion in the 64 diagonal blocks, templated <DIAG>,
//          self <=> dd == nf*16 - mf*16 - rg).
//   merge: min over 16 (n1,ss1) slices -> mean hinge (device atomics).
// fbT8[kc*8192 + row] = features[row][kc*8..kc*8+7], kc=0..15.

#define BN 8192
#define MARGIN_F 1.0f
#define EPS_F 1e-5f

typedef __attribute__((ext_vector_type(8))) short short8;
typedef __attribute__((ext_vector_type(4))) float floatx4;

__device__ __forceinline__ unsigned short bf16_rne(float x, float& r) {
    unsigned u = __float_as_uint(x);
    u += 0x7FFF + ((u >> 16) & 1);
    unsigned short h = (unsigned short)(u >> 16);
    r = __uint_as_float(((unsigned)h) << 16);
    return h;
}

// 8 threads/row (256 blocks): bf16 convert, K-major write, lsq=(sq, lblbits)
// from ROUNDED values. Also zero-inits g_acc/counter.
__global__ __launch_bounds__(256) void prep_kernel(const float* __restrict__ f,
                                                   const int* __restrict__ lbl,
                                                   short8* __restrict__ fbT,
                                                   float2* __restrict__ lsq,
                                                   float* __restrict__ g_acc,
                                                   unsigned* __restrict__ counter) {
    int gid = blockIdx.x * 256 + threadIdx.x;  // 0..65535
    if (gid == 0) { *g_acc = 0.f; *counter = 0u; }
    int row = gid >> 3, part = gid & 7;
    const float4* f4 = (const float4*)f + (size_t)row * 32 + part * 4;
    float s = 0.f;
#pragma unroll
    for (int cc = 0; cc < 2; ++cc) {  // chunk kc = part*2 + cc
        float4 v0 = f4[cc * 2], v1 = f4[cc * 2 + 1];
        float r0, r1, r2, r3, r4, r5, r6, r7;
        short8 o;
        o[0] = (short)bf16_rne(v0.x, r0);
        o[1] = (short)bf16_rne(v0.y, r1);
        o[2] = (short)bf16_rne(v0.z, r2);
        o[3] = (short)bf16_rne(v0.w, r3);
        o[4] = (short)bf16_rne(v1.x, r4);
        o[5] = (short)bf16_rne(v1.y, r5);
        o[6] = (short)bf16_rne(v1.z, r6);
        o[7] = (short)bf16_rne(v1.w, r7);
        fbT[(size_t)(part * 2 + cc) * BN + row] = o;
        s += r0 * r0 + r1 * r1 + r2 * r2 + r3 * r3 +
             r4 * r4 + r5 * r5 + r6 * r6 + r7 * r7;
    }
    s += __shfl_xor(s, 1, 8);
    s += __shfl_xor(s, 2, 8);
    s += __shfl_xor(s, 4, 8);
    if (part == 0) {
        float2 p;
        p.x = s;
        p.y = __int_as_float(lbl[row]);
        lsq[row] = p;
    }
}

// Stage one 32-col B-tile (16 chunks x 32 cols = 8 KB) into LDS: each wave
// issues 2 global_load_lds(16B). LDS dest is wave-uniform; HW adds lane*16.
// Layout: tile[kc*32 + col], kc = lane>>5 within each 64-slot instr.
__device__ __forceinline__ void stage_tile(const short8* __restrict__ fbT,
                                           short8* tile, int j0, int wv, int lane) {
#pragma unroll
    for (int it = 0; it < 2; ++it) {
        int s = wv * 128 + it * 64;  // wave-uniform slot base
        int kc = (s >> 5) + (lane >> 5);
        int col = lane & 31;
        const short8* g = fbT + ((size_t)kc * BN + j0 + col);
        __builtin_amdgcn_global_load_lds(
            (const __attribute__((address_space(1))) void*)g,
            (__attribute__((address_space(3))) void*)(tile + s),
            16, 0, 0);
    }
}

// The 16-jt inner loop, templated on whether this block's i-range intersects
// its j-stripe (only 64 of 1024 blocks). DIAG adds the index-based self
// exclusion for ss1: self <=> dd == nf*16 - mf*16 - rg (comparand is a
// compile-time constant per unrolled element).
template <bool DIAG>
__device__ __forceinline__ void jt_loop(const short8* __restrict__ fbT,
                                        short8 (*Bt)[512],
                                        const float2* lsq_sh,
                                        const short8 a[2][4], const int li[2][4],
                                        float n1[2][4], float ss1[2][4],
                                        int wv, int lane, int c, int q,
                                        int i0, int jb) {
    for (int jt = 0; jt < 16; ++jt) {
        const short8* cur = Bt[jt & 1];
        // prefetch next tile NOW; it lands during this tile's compute
        if (jt < 15) stage_tile(fbT, Bt[1 - (jt & 1)], jb + (jt + 1) * 32, wv, lane);

        int ljv[2]; float sjv[2];
#pragma unroll
        for (int nf = 0; nf < 2; ++nf) {
            float2 p = lsq_sh[jt * 32 + nf * 16 + c];
            sjv[nf] = p.x;
            ljv[nf] = __float_as_int(p.y);
        }

        // i - j = dd + mf*16 + rg - nf*16
        int dd = DIAG ? ((i0 + q * 4) - (jb + jt * 32 + c)) : 0;

        // b-frags from LDS (contiguous 1KB rows per instr, conflict-free)
        short8 b[4][2];
#pragma unroll
        for (int ks = 0; ks < 4; ++ks)
#pragma unroll
            for (int nf = 0; nf < 2; ++nf)
                b[ks][nf] = cur[(ks * 4 + q) * 32 + nf * 16 + c];

        floatx4 acc[2][2];
#pragma unroll
        for (int mf = 0; mf < 2; ++mf)
#pragma unroll
            for (int nf = 0; nf < 2; ++nf) acc[mf][nf] = (floatx4)0.f;

#pragma unroll
        for (int ks = 0; ks < 4; ++ks)
#pragma unroll
            for (int mf = 0; mf < 2; ++mf)
#pragma unroll
                for (int nf = 0; nf < 2; ++nf)
                    acc[mf][nf] = __builtin_amdgcn_mfma_f32_16x16x32_bf16(
                        a[mf][ks], b[ks][nf], acc[mf][nf], 0, 0, 0);

#pragma unroll
        for (int nf = 0; nf < 2; ++nf)
#pragma unroll
            for (int mf = 0; mf < 2; ++mf)
#pragma unroll
                for (int rg = 0; rg < 4; ++rg) {
                    float v = fmaf(-2.0f, acc[mf][nf][rg], sjv[nf]);
                    bool same = (li[mf][rg] == ljv[nf]);
                    float vd = same ? INFINITY : v;
                    n1[mf][rg] = fminf(n1[mf][rg], vd);
                    bool excl = same;
                    if (DIAG) excl = same && (dd != (nf * 16 - mf * 16 - rg));
                    float vs = excl ? v : INFINITY;
                    ss1[mf][rg] = fminf(ss1[mf][rg], vs);
                }
        // barrier at END: (a) all reads of cur done before next jt's stage
        // overwrites it, (b) the stage issued above has had the whole
        // compute phase to land -> drain ~free. Other 3 blocks on the CU
        // cover the drain.
        __syncthreads();
    }
}

// Fused work kernel: 1024 blocks (4/CU), 4 waves, wave tile 32x32.
// Per element: n1 = min diff-class v, ss1 = min same-class v excl self.
__global__ __launch_bounds__(256, 4) void work_kernel(const short8* __restrict__ fbT,
                                                      const float2* __restrict__ lsq,
                                                      float* __restrict__ part_n1,
                                                      float* __restrict__ part_p1) {
    const int t = threadIdx.x;
    const int lane = t & 63;
    const int wv = t >> 6;
    const int q = lane >> 4, c = lane & 15;
    const int bid = blockIdx.x;

    __shared__ short8 Bt[2][512];   // 2 x 8 KB double buffer, [kc*32 + col]
    __shared__ float2 lsq_sh[512];  // block's j-stripe (sq, lblbits) — 4 KB

    const int ib = bid & 63;         // 64 i-blocks of 128 rows
    const int g = bid >> 6;          // 16 stripes
    const int i0 = ib * 128 + wv * 32;
    const int jb = g * 512;
    const bool diag = ((ib >> 2) == g);  // i-range intersects j-stripe

    stage_tile(fbT, Bt[0], jb, wv, lane);  // tile 0 in flight

    // stage the stripe's (sq,label) once: 512 float2, 2 per thread
    lsq_sh[t] = lsq[jb + t];
    lsq_sh[t + 256] = lsq[jb + t + 256];

    short8 a[2][4];
#pragma unroll
    for (int mf = 0; mf < 2; ++mf) {
        int row = i0 + mf * 16 + c;
#pragma unroll
        for (int ks = 0; ks < 4; ++ks)
            a[mf][ks] = fbT[(size_t)(ks * 4 + q) * BN + row];
    }
    int li[2][4];
#pragma unroll
    for (int mf = 0; mf < 2; ++mf)
#pragma unroll
        for (int rg = 0; rg < 4; ++rg)
            li[mf][rg] = __float_as_int(lsq[i0 + mf * 16 + q * 4 + rg].y);

    float n1[2][4], ss1[2][4];
#pragma unroll
    for (int mf = 0; mf < 2; ++mf)
#pragma unroll
        for (int rg = 0; rg < 4; ++rg) {
            n1[mf][rg] = INFINITY;
            ss1[mf][rg] = INFINITY;
        }

    __syncthreads();  // tile 0 + lsq_sh resident

    if (diag)
        jt_loop<true>(fbT, Bt, lsq_sh, a, li, n1, ss1, wv, lane, c, q, i0, jb);
    else
        jt_loop<false>(fbT, Bt, lsq_sh, a, li, n1, ss1, wv, lane, c, q, i0, jb);

    // min-reduce across the 16 c-lanes sharing each accumulator row
#pragma unroll
    for (int m = 1; m < 16; m <<= 1) {
#pragma unroll
        for (int mf = 0; mf < 2; ++mf)
#pragma unroll
            for (int rg = 0; rg < 4; ++rg) {
                n1[mf][rg] = fminf(n1[mf][rg], __shfl_xor(n1[mf][rg], m, 16));
                ss1[mf][rg] = fminf(ss1[mf][rg], __shfl_xor(ss1[mf][rg], m, 16));
            }
    }
    if (c == 0) {
#pragma unroll
        for (int mf = 0; mf < 2; ++mf)
#pragma unroll
            for (int rg = 0; rg < 4; ++rg) {
                int idx = g * BN + i0 + mf * 16 + q * 4 + rg;
                part_n1[idx] = n1[mf][rg];
                part_p1[idx] = ss1[mf][rg];
            }
    }
}

// combine 16 (n1,ss1) slices -> hinge; atomic sum; last block writes mean
__global__ __launch_bounds__(128) void merge_kernel(const float* __restrict__ part_n1,
                                                    const float* __restrict__ part_p1,
                                                    const float2* __restrict__ lsq,
                                                    float* __restrict__ g_acc,
                                                    unsigned* __restrict__ counter,
                                                    float* __restrict__ out) {
    int r = blockIdx.x * 128 + threadIdx.x;
    float n = INFINITY, ss = INFINITY;
#pragma unroll
    for (int k = 0; k < 16; ++k) {
        n = fminf(n, part_n1[k * BN + r]);
        ss = fminf(ss, part_p1[k * BN + r]);
    }
    float si = lsq[r].x;
    float pos = sqrtf(fmaxf(si + ss + EPS_F, 0.f));
    float neg = sqrtf(fmaxf(si + n + EPS_F, 0.f));
    float h = fmaxf(MARGIN_F + pos - neg, 0.f);
    __shared__ float red[2];
#pragma unroll
    for (int m = 32; m >= 1; m >>= 1) h += __shfl_down(h, m, 64);
    if ((threadIdx.x & 63) == 0) red[threadIdx.x >> 6] = h;
    __syncthreads();
    if (threadIdx.x == 0) {
        atomicAdd(g_acc, red[0] + red[1]);
        __threadfence();
        unsigned old = atomicAdd(counter, 1u);
        if (old == 63u) {
            float tot = atomicAdd(g_acc, 0.0f);
            out[0] = tot / (float)BN;
        }
    }
}

extern "C" void kernel_launch(void* const* d_in, const int* in_sizes, int n_in,
                              void* d_out, int out_size, void* d_ws, size_t ws_size,
                              hipStream_t stream) {
    const float* f = (const float*)d_in[0];
    const int* lbl = (const int*)d_in[1];
    char* ws = (char*)d_ws;
    float2* lsq = (float2*)ws;                                  // 64 KB
    short8* fbT = (short8*)(ws + 65536);                        // 2 MB
    float* part_n1 = (float*)(ws + 65536 + 2097152);            // 512 KB
    float* part_p1 = (float*)(ws + 65536 + 2097152 + 524288);   // 512 KB
    float* g_acc = (float*)(ws + 65536 + 2097152 + 1048576);
    unsigned* counter = (unsigned*)(g_acc + 1);
    float* out = (float*)d_out;

    prep_kernel<<<256, 256, 0, stream>>>(f, lbl, fbT, lsq, g_acc, counter);
    work_kernel<<<1024, 256, 0, stream>>>(fbT, lsq, part_n1, part_p1);
    merge_kernel<<<64, 128, 0, stream>>>(part_n1, part_p1, lsq, g_acc, counter, out);
}